// Round 3
// baseline (117.692 us; speedup 1.0000x reference)
//
#include <hip/hip_runtime.h>

#define NV 8
#define NB 16
#define LMAX 4096
#define ND 1024
#define CHUNK 64
#define NCHUNK (LMAX / CHUNK)   // 64 chunks -> 1024 blocks
#define EPS_ 1e-6f
// exp(-10*s) == exp2(s * (-10*log2(e)))
#define NEXP10 (-14.426950408889634f)

#define NUM_FLOATS (NB * NV * ND)          // 131072
#define DEN_FLOATS (NB * NV)               // 128
#define WS_FLOAT4S ((NUM_FLOATS + DEN_FLOATS) / 4)   // 32800

__global__ __launch_bounds__(256) void dvs_zero(float4* ws) {
    const int idx = blockIdx.x * 256 + threadIdx.x;
    if (idx < WS_FLOAT4S) ws[idx] = make_float4(0.f, 0.f, 0.f, 0.f);
}

// ws layout: num[NB][NV][ND] floats, then den[NB][NV] floats
__global__ __launch_bounds__(256, 3) void dvs_accum(
    const float* __restrict__ v_pad,
    const float* __restrict__ centers,
    const int* __restrict__ grid_thws,
    float* __restrict__ ws_num,
    float* __restrict__ ws_den)
{
    const int b     = blockIdx.x >> 6;      // / NCHUNK
    const int chunk = blockIdx.x & (NCHUNK - 1);
    const int H  = grid_thws[b * 3 + 1];
    const int W  = grid_thws[b * 3 + 2];
    const int HW = H * W;
    const int l0 = chunk * CHUNK;
    if (l0 >= HW) return;                   // fully-masked chunk: read nothing

    float cx[NV], cy[NV];
#pragma unroll
    for (int v = 0; v < NV; ++v) {
        float2 c = ((const float2*)centers)[b * NV + v];
        cx[v] = c.x; cy[v] = c.y;
    }
    const float invH = 1.0f / (float)H;
    const float invW = 1.0f / (float)W;

    const int t = threadIdx.x;              // thread owns d = 4t..4t+3
    const float4* __restrict__ src =
        (const float4*)v_pad + ((size_t)b * LMAX + l0) * (ND / 4) + t;
    // row r of this chunk is src[r * 256]

    float acc[NV][4];
    float dsum[NV];
#pragma unroll
    for (int v = 0; v < NV; ++v) {
        dsum[v] = 0.0f;
#pragma unroll
        for (int k = 0; k < 4; ++k) acc[v][k] = 0.0f;
    }

    // incremental (i,j): no per-row integer division
    int i = l0 / W;
    int j = l0 - i * W;
    int lrow = l0;

    auto proc = [&](const float4 r4) {
        const float y = ((float)i + 0.5f) * invH;
        const float x = ((float)j + 0.5f) * invW;
        const float vmask = (lrow < HW) ? 1.0f : 0.0f;
#pragma unroll
        for (int v = 0; v < NV; ++v) {
            const float dx = cx[v] - x;
            const float dy = cy[v] - y;
            const float s  = fmaf(dy, dy, dx * dx);
            const float m  = exp2f(s * NEXP10) * vmask;   // one v_exp_f32
            dsum[v] += m;
            acc[v][0] = fmaf(m, r4.x, acc[v][0]);
            acc[v][1] = fmaf(m, r4.y, acc[v][1]);
            acc[v][2] = fmaf(m, r4.z, acc[v][2]);
            acc[v][3] = fmaf(m, r4.w, acc[v][3]);
        }
        ++lrow;
        if (++j == W) { j = 0; ++i; }
    };

    // 4-deep software pipeline over the fixed 64-row chunk.
    float4 c0 = src[0 * 256];
    float4 c1 = src[1 * 256];
    float4 c2 = src[2 * 256];
    float4 c3 = src[3 * 256];
    for (int r = 0; r < CHUNK; r += 4) {
        float4 n0, n1, n2, n3;
        if (r + 4 < CHUNK) {                // uniform branch
            n0 = src[(r + 4) * 256];
            n1 = src[(r + 5) * 256];
            n2 = src[(r + 6) * 256];
            n3 = src[(r + 7) * 256];
        }
        proc(c0); proc(c1); proc(c2); proc(c3);
        c0 = n0; c1 = n1; c2 = n2; c3 = n3;
    }

    float* nb_ = ws_num + (size_t)(b * NV) * ND + t * 4;
#pragma unroll
    for (int v = 0; v < NV; ++v) {
        atomicAdd(nb_ + v * ND + 0, acc[v][0]);
        atomicAdd(nb_ + v * ND + 1, acc[v][1]);
        atomicAdd(nb_ + v * ND + 2, acc[v][2]);
        atomicAdd(nb_ + v * ND + 3, acc[v][3]);
    }
    if (t == 0) {
#pragma unroll
        for (int v = 0; v < NV; ++v) atomicAdd(&ws_den[b * NV + v], dsum[v]);
    }
}

__global__ __launch_bounds__(256) void dvs_final(
    const float* __restrict__ ws_num,
    const float* __restrict__ ws_den,
    float* __restrict__ out)
{
    const int idx = blockIdx.x * 256 + threadIdx.x;   // NB*NV*ND threads
    const int bv  = idx >> 10;                        // / ND
    out[idx] = ws_num[idx] / (ws_den[bv] + EPS_);
}

extern "C" void kernel_launch(void* const* d_in, const int* in_sizes, int n_in,
                              void* d_out, int out_size, void* d_ws, size_t ws_size,
                              hipStream_t stream) {
    const float* v_pad     = (const float*)d_in[0];
    const float* centers   = (const float*)d_in[1];
    // d_in[2] = v_len (== H*W), unused
    const int*   grid_thws = (const int*)d_in[3];

    float* ws_num = (float*)d_ws;
    float* ws_den = ws_num + (size_t)NUM_FLOATS;

    dvs_zero<<<(WS_FLOAT4S + 255) / 256, 256, 0, stream>>>((float4*)d_ws);
    dvs_accum<<<NB * NCHUNK, 256, 0, stream>>>(v_pad, centers, grid_thws, ws_num, ws_den);
    dvs_final<<<(NB * NV * ND) / 256, 256, 0, stream>>>(ws_num, ws_den, (float*)d_out);
}

// Round 4
// 70.670 us; speedup vs baseline: 1.6654x; 1.6654x over previous
//
#include <hip/hip_runtime.h>

#define NV 8
#define NB 16
#define LMAX 4096
#define ND 1024
#define CHUNK 64
#define NCHUNK (LMAX / CHUNK)   // 64 chunks -> 1024 blocks
#define EPS_ 1e-6f
// exp(-10*s) == exp2(s * (-10*log2(e)))
#define NEXP10 (-14.426950408889634f)

// ws layout: pnum[NB][NCHUNK][NV][ND] floats (32 MB), then pden[NB][NCHUNK][NV]
#define PNUM_FLOATS ((size_t)NB * NCHUNK * NV * ND)

__global__ __launch_bounds__(256) void dvs_accum(
    const float* __restrict__ v_pad,
    const float* __restrict__ centers,
    const int* __restrict__ grid_thws,
    float* __restrict__ pnum,
    float* __restrict__ pden)
{
    const int b     = blockIdx.x >> 6;      // / NCHUNK
    const int chunk = blockIdx.x & (NCHUNK - 1);
    const int H  = grid_thws[b * 3 + 1];
    const int W  = grid_thws[b * 3 + 2];
    const int HW = H * W;
    const int l0 = chunk * CHUNK;
    if (l0 >= HW) return;                   // fully-masked chunk: no reads, no writes

    float cx[NV], cy[NV];
#pragma unroll
    for (int v = 0; v < NV; ++v) {
        float2 c = ((const float2*)centers)[b * NV + v];
        cx[v] = c.x; cy[v] = c.y;
    }
    const float invH = 1.0f / (float)H;
    const float invW = 1.0f / (float)W;

    const int t = threadIdx.x;              // thread owns d = 4t..4t+3
    const float4* __restrict__ src =
        (const float4*)v_pad + ((size_t)b * LMAX + l0) * (ND / 4) + t;

    float acc[NV][4];
    float dsum[NV];
#pragma unroll
    for (int v = 0; v < NV; ++v) {
        dsum[v] = 0.0f;
#pragma unroll
        for (int k = 0; k < 4; ++k) acc[v][k] = 0.0f;
    }

    int i = l0 / W;
    int j = l0 - i * W;
    int lrow = l0;

    auto proc = [&](const float4 r4) {
        const float y = ((float)i + 0.5f) * invH;
        const float x = ((float)j + 0.5f) * invW;
        const float vmask = (lrow < HW) ? 1.0f : 0.0f;
#pragma unroll
        for (int v = 0; v < NV; ++v) {
            const float dx = cx[v] - x;
            const float dy = cy[v] - y;
            const float s  = fmaf(dy, dy, dx * dx);
            const float m  = exp2f(s * NEXP10) * vmask;   // one v_exp_f32
            dsum[v] += m;
            acc[v][0] = fmaf(m, r4.x, acc[v][0]);
            acc[v][1] = fmaf(m, r4.y, acc[v][1]);
            acc[v][2] = fmaf(m, r4.z, acc[v][2]);
            acc[v][3] = fmaf(m, r4.w, acc[v][3]);
        }
        ++lrow;
        if (++j == W) { j = 0; ++i; }
    };

    // 2-deep pair pipeline over the fixed 64-row chunk.
    float4 c0 = src[0 * 256];
    float4 c1 = src[1 * 256];
    for (int r = 0; r < CHUNK; r += 2) {
        float4 n0, n1;
        if (r + 2 < CHUNK) {                // uniform branch
            n0 = src[(r + 2) * 256];
            n1 = src[(r + 3) * 256];
        }
        proc(c0); proc(c1);
        c0 = n0; c1 = n1;
    }

    // private partial store — no atomics, no contention
    const size_t pbase = (size_t)(b * NCHUNK + chunk) * NV;
    float4* np_ = (float4*)pnum;
#pragma unroll
    for (int v = 0; v < NV; ++v)
        np_[(pbase + v) * (ND / 4) + t] =
            make_float4(acc[v][0], acc[v][1], acc[v][2], acc[v][3]);
    if (t == 0) {
#pragma unroll
        for (int v = 0; v < NV; ++v) pden[pbase + v] = dsum[v];  // static reg index
    }
}

__global__ __launch_bounds__(256) void dvs_reduce(
    const float* __restrict__ pnum,
    const float* __restrict__ pden,
    const int* __restrict__ grid_thws,
    float* __restrict__ out)
{
    const int b = blockIdx.x >> 3;          // NB*NV = 128 blocks
    const int v = blockIdx.x & (NV - 1);
    const int H  = grid_thws[b * 3 + 1];
    const int W  = grid_thws[b * 3 + 2];
    const int nc = (H * W + CHUNK - 1) / CHUNK;   // active chunks for this b
    const int t  = threadIdx.x;

    const float4* np_ = (const float4*)pnum;
    float4 s0 = make_float4(0.f, 0.f, 0.f, 0.f);
    float4 s1 = make_float4(0.f, 0.f, 0.f, 0.f);
    float den0 = 0.f, den1 = 0.f;
    int c = 0;
    for (; c + 2 <= nc; c += 2) {           // 2-way ILP
        const size_t i0 = (size_t)((b * NCHUNK + c)     * NV + v);
        const size_t i1 = (size_t)((b * NCHUNK + c + 1) * NV + v);
        float4 p0 = np_[i0 * (ND / 4) + t];
        float4 p1 = np_[i1 * (ND / 4) + t];
        s0.x += p0.x; s0.y += p0.y; s0.z += p0.z; s0.w += p0.w;
        s1.x += p1.x; s1.y += p1.y; s1.z += p1.z; s1.w += p1.w;
        den0 += pden[i0];
        den1 += pden[i1];
    }
    if (c < nc) {
        const size_t i0 = (size_t)((b * NCHUNK + c) * NV + v);
        float4 p0 = np_[i0 * (ND / 4) + t];
        s0.x += p0.x; s0.y += p0.y; s0.z += p0.z; s0.w += p0.w;
        den0 += pden[i0];
    }
    const float inv = 1.0f / (den0 + den1 + EPS_);
    float4 o = make_float4((s0.x + s1.x) * inv, (s0.y + s1.y) * inv,
                           (s0.z + s1.z) * inv, (s0.w + s1.w) * inv);
    ((float4*)out)[(size_t)(b * NV + v) * (ND / 4) + t] = o;
}

extern "C" void kernel_launch(void* const* d_in, const int* in_sizes, int n_in,
                              void* d_out, int out_size, void* d_ws, size_t ws_size,
                              hipStream_t stream) {
    const float* v_pad     = (const float*)d_in[0];
    const float* centers   = (const float*)d_in[1];
    // d_in[2] = v_len (== H*W), unused
    const int*   grid_thws = (const int*)d_in[3];

    float* pnum = (float*)d_ws;
    float* pden = pnum + PNUM_FLOATS;

    dvs_accum<<<NB * NCHUNK, 256, 0, stream>>>(v_pad, centers, grid_thws, pnum, pden);
    dvs_reduce<<<NB * NV, 256, 0, stream>>>(pnum, pden, grid_thws, (float*)d_out);
}

// Round 5
// 35.100 us; speedup vs baseline: 3.3531x; 2.0134x over previous
//
#include <hip/hip_runtime.h>

#define NV 8
#define NB 16
#define LMAX 4096
#define ND 1024
#define CHUNK 64
#define NCHUNK (LMAX / CHUNK)   // 64 chunks -> 1024 blocks
#define EPS_ 1e-6f
// exp(-10*s) == exp2(s * (-10*log2(e)))
#define NEXP10 (-14.426950408889634f)

// ws layout: pnum[NB][NCHUNK][NV][ND] floats (32 MB), then pden[NB][NCHUNK][NV]
#define PNUM_FLOATS ((size_t)NB * NCHUNK * NV * ND)

__global__ __launch_bounds__(256, 4) void dvs_accum(
    const float* __restrict__ v_pad,
    const float* __restrict__ centers,
    const int* __restrict__ grid_thws,
    float* __restrict__ pnum,
    float* __restrict__ pden)
{
    const int b     = blockIdx.x >> 6;      // / NCHUNK
    const int chunk = blockIdx.x & (NCHUNK - 1);
    const int H  = grid_thws[b * 3 + 1];
    const int W  = grid_thws[b * 3 + 2];
    const int HW = H * W;
    const int l0 = chunk * CHUNK;
    if (l0 >= HW) return;                   // fully-masked chunk: no reads, no writes

    __shared__ __align__(16) float wlds[CHUNK][NV];   // 2 KB: weights w[row][view]

    const int t = threadIdx.x;
    const float invH = 1.0f / (float)H;
    const float invW = 1.0f / (float)W;

    // ---- weight phase: 512 weights, 2 per thread (computed ONCE per block,
    //      not once per thread-row as before)
#pragma unroll
    for (int g = 0; g < 2; ++g) {
        const int idx = t + g * 256;
        const int row = idx >> 3;           // 0..63
        const int v   = idx & 7;
        const int l   = l0 + row;
        const int i   = l / W;              // 2 int divs per thread, once per block
        const int j   = l - i * W;
        const float y = ((float)i + 0.5f) * invH;
        const float x = ((float)j + 0.5f) * invW;
        const float2 c = ((const float2*)centers)[b * NV + v];
        const float dx = c.x - x;
        const float dy = c.y - y;
        const float s  = fmaf(dy, dy, dx * dx);
        wlds[row][v] = (l < HW) ? exp2f(s * NEXP10) : 0.0f;
    }
    __syncthreads();

    // ---- pden straight from LDS (removes dsum from the hot loop)
    const size_t pbase = (size_t)(b * NCHUNK + chunk) * NV;
    if (t < NV) {
        float s = 0.0f;
#pragma unroll
        for (int r = 0; r < CHUNK; ++r) s += wlds[r][t];
        pden[pbase + t] = s;
    }

    // ---- main loop: 1 dwordx4 load + 2 broadcast ds_read_b128 + 32 FMA per row
    const float4* __restrict__ src =
        (const float4*)v_pad + ((size_t)b * LMAX + l0) * (ND / 4) + t;

    float acc[NV][4];
#pragma unroll
    for (int v = 0; v < NV; ++v)
#pragma unroll
        for (int k = 0; k < 4; ++k) acc[v][k] = 0.0f;

    auto proc = [&](const int r, const float4 r4) {
        float w[NV];
        *(float4*)&w[0] = *(const float4*)&wlds[r][0];
        *(float4*)&w[4] = *(const float4*)&wlds[r][4];
#pragma unroll
        for (int v = 0; v < NV; ++v) {
            acc[v][0] = fmaf(w[v], r4.x, acc[v][0]);
            acc[v][1] = fmaf(w[v], r4.y, acc[v][1]);
            acc[v][2] = fmaf(w[v], r4.z, acc[v][2]);
            acc[v][3] = fmaf(w[v], r4.w, acc[v][3]);
        }
    };

    // 4-deep software pipeline over the fixed 64-row chunk
    float4 c0 = src[0 * 256];
    float4 c1 = src[1 * 256];
    float4 c2 = src[2 * 256];
    float4 c3 = src[3 * 256];
    for (int r = 0; r < CHUNK; r += 4) {
        float4 n0 = c0, n1 = c1, n2 = c2, n3 = c3;
        if (r + 4 < CHUNK) {                // uniform branch
            n0 = src[(r + 4) * 256];
            n1 = src[(r + 5) * 256];
            n2 = src[(r + 6) * 256];
            n3 = src[(r + 7) * 256];
        }
        proc(r + 0, c0); proc(r + 1, c1); proc(r + 2, c2); proc(r + 3, c3);
        c0 = n0; c1 = n1; c2 = n2; c3 = n3;
    }

    // private partial store — no atomics
    float4* np_ = (float4*)pnum;
#pragma unroll
    for (int v = 0; v < NV; ++v)
        np_[(pbase + v) * (ND / 4) + t] =
            make_float4(acc[v][0], acc[v][1], acc[v][2], acc[v][3]);
}

__global__ __launch_bounds__(256) void dvs_reduce(
    const float* __restrict__ pnum,
    const float* __restrict__ pden,
    const int* __restrict__ grid_thws,
    float* __restrict__ out)
{
    const int b = blockIdx.x >> 3;          // NB*NV = 128 blocks
    const int v = blockIdx.x & (NV - 1);
    const int HW = grid_thws[b * 3 + 1] * grid_thws[b * 3 + 2];
    const int nc = (HW + CHUNK - 1) / CHUNK;
    const int t  = threadIdx.x;

    const float4* np_ = (const float4*)pnum;
    const size_t cstride = (size_t)NV * (ND / 4);   // float4s between chunks
    const size_t base = ((size_t)b * NCHUNK * NV + v) * (ND / 4) + t;
    const int dbase = b * NCHUNK * NV + v;

    float4 s0 = make_float4(0.f, 0.f, 0.f, 0.f), s1 = s0, s2 = s0, s3 = s0;
    float d0 = 0.f, d1 = 0.f, d2 = 0.f, d3 = 0.f;
    int c = 0;
    for (; c + 4 <= nc; c += 4) {           // 4-way ILP, 4 loads in flight
        float4 p0 = np_[base + (size_t)(c + 0) * cstride];
        float4 p1 = np_[base + (size_t)(c + 1) * cstride];
        float4 p2 = np_[base + (size_t)(c + 2) * cstride];
        float4 p3 = np_[base + (size_t)(c + 3) * cstride];
        d0 += pden[dbase + (c + 0) * NV];
        d1 += pden[dbase + (c + 1) * NV];
        d2 += pden[dbase + (c + 2) * NV];
        d3 += pden[dbase + (c + 3) * NV];
        s0.x += p0.x; s0.y += p0.y; s0.z += p0.z; s0.w += p0.w;
        s1.x += p1.x; s1.y += p1.y; s1.z += p1.z; s1.w += p1.w;
        s2.x += p2.x; s2.y += p2.y; s2.z += p2.z; s2.w += p2.w;
        s3.x += p3.x; s3.y += p3.y; s3.z += p3.z; s3.w += p3.w;
    }
    for (; c < nc; ++c) {
        float4 p0 = np_[base + (size_t)c * cstride];
        d0 += pden[dbase + c * NV];
        s0.x += p0.x; s0.y += p0.y; s0.z += p0.z; s0.w += p0.w;
    }
    const float inv = 1.0f / (d0 + d1 + d2 + d3 + EPS_);
    float4 o = make_float4((s0.x + s1.x + s2.x + s3.x) * inv,
                           (s0.y + s1.y + s2.y + s3.y) * inv,
                           (s0.z + s1.z + s2.z + s3.z) * inv,
                           (s0.w + s1.w + s2.w + s3.w) * inv);
    ((float4*)out)[(size_t)(b * NV + v) * (ND / 4) + t] = o;
}

extern "C" void kernel_launch(void* const* d_in, const int* in_sizes, int n_in,
                              void* d_out, int out_size, void* d_ws, size_t ws_size,
                              hipStream_t stream) {
    const float* v_pad     = (const float*)d_in[0];
    const float* centers   = (const float*)d_in[1];
    // d_in[2] = v_len (== H*W), unused
    const int*   grid_thws = (const int*)d_in[3];

    float* pnum = (float*)d_ws;
    float* pden = pnum + PNUM_FLOATS;

    dvs_accum<<<NB * NCHUNK, 256, 0, stream>>>(v_pad, centers, grid_thws, pnum, pden);
    dvs_reduce<<<NB * NV, 256, 0, stream>>>(pnum, pden, grid_thws, (float*)d_out);
}